// Round 10
// baseline (602.776 us; speedup 1.0000x reference)
//
#include <hip/hip_runtime.h>

// R10 (from R9 = 451 µs): fuse the 6-dispatch M-cluster chain (seg_gather ->
// f3-gemm -> M-agg -> f4-gemm -> M-agg -> f4_1-gemm) into ONE 256-block kernel
// with software grid barriers (256 blocks <= 256 CUs guaranteed co-resident;
// atomicAdd arrive + __threadfence device-scope fence). Removes 5 launch gaps
// + ramp tails; bodies refactored into shared __device__ functions (bit-identical).
// Carried: sorted slabs + striped btot, cooperative build gather, fused
// wprep+bin+f1g, permuted activations, K-permuted weights, R0-shape agg.

#define N_PTS   100000
#define M_CL    12500
#define E0_N    1600000
#define E1_N    400000

#define NB      256
#define NCOPY   32
#define RANGE0  391
#define RANGE1  49
#define NCH0    782
#define NCH1    196
#define NCHL    49
#define CAP0    7168

#define LSTR    72           // LDS row stride (shorts): 144 B

typedef unsigned short ushortT;
typedef short  short8 __attribute__((ext_vector_type(8)));
typedef short  s4v    __attribute__((ext_vector_type(4)));
typedef float  v4f    __attribute__((ext_vector_type(4)));
typedef _Float16 h2   __attribute__((ext_vector_type(2)));
typedef unsigned u4v  __attribute__((ext_vector_type(4)));

__device__ inline ushortT f2bf(float x){
  union{float f; unsigned u;} v; v.f = x;
  unsigned r = v.u + 0x7fffu + ((v.u >> 16) & 1u);   // RNE
  return (ushortT)(r >> 16);
}
__device__ inline float bf2f(ushortT h){
  union{unsigned u; float f;} v; v.u = ((unsigned)h) << 16;
  return v.f;
}
__device__ inline ushortT f2h(float x){
  union{_Float16 h; ushortT u;} v; v.h = (_Float16)x;
  return v.u;
}
__device__ inline float h2f(ushortT u){
  union{ushortT u; _Float16 h;} v; v.u = u;
  return (float)v.h;
}
__device__ inline h2 pkmax(h2 a, h2 b){ return __builtin_elementwise_max(a, b); }
__device__ inline h2 u2h(unsigned u){ union{unsigned u; h2 h;} v{u}; return v.h; }

struct WSrc { const float* p[22]; };

// ============================ software grid barrier (co-resident blocks only) ============================

__device__ inline void gridbar(int* bar, int nblk){
  __syncthreads();
  if (threadIdx.x == 0){
    __threadfence();                 // release: flush data writes to device scope
    atomicAdd(bar, 1);
    while (atomicAdd(bar, 0) < nblk) {}
    __threadfence();                 // acquire: invalidate for remote writes
  }
  __syncthreads();
}

// ============================ chunk sort (binning, no global scatter) ============================

template<int RANGE, bool LAB>
__device__ void sort_chunk(const int* __restrict__ edges, int E, int c,
                           unsigned* __restrict__ slab, int* __restrict__ offC,
                           int* __restrict__ btot,
                           unsigned* slds, int* hist, int* pfx){
  int tid = threadIdx.x;
  int base = c*2048;
  int cnt = E - base; if (cnt > 2048) cnt = 2048;
  hist[tid] = 0;
  __syncthreads();
  int bk[8]; unsigned pk[8];
  #pragma unroll
  for (int r=0;r<8;++r){
    int e = base + r*256 + tid;
    bk[r] = -1; pk[r] = 0;
    if (e < E){
      int s, d;
      if (LAB){ s = e; d = edges[e]; }
      else    { int2 ed = ((const int2*)edges)[e]; s = ed.x; d = ed.y; }
      int b = d / RANGE;
      bk[r] = b;
      pk[r] = ((unsigned)s << 11) | (unsigned)(d - b*RANGE);
      atomicAdd(&hist[b], 1);
    }
  }
  __syncthreads();
  int own = hist[tid];
  pfx[tid] = own;
  __syncthreads();
  for (int st=1; st<256; st<<=1){
    int x = (tid >= st) ? pfx[tid-st] : 0;
    __syncthreads();
    pfx[tid] += x;
    __syncthreads();
  }
  int excl = pfx[tid] - own;
  offC[(size_t)c*257 + tid] = excl;
  if (tid == 0) offC[(size_t)c*257 + 256] = cnt;
  if (own) atomicAdd(&btot[(c & (NCOPY-1))*NB + tid], own);
  hist[tid] = excl;          // running cursor
  __syncthreads();
  #pragma unroll
  for (int r=0;r<8;++r){
    if (bk[r] >= 0){
      int pos = atomicAdd(&hist[bk[r]], 1);
      slds[pos] = pk[r];
    }
  }
  __syncthreads();
  unsigned* sg = slab + (size_t)c*2048;
  for (int i=tid; i<cnt; i+=256) sg[i] = slds[i];
}

// ============================ CSR build (cooperative slab gather) ============================

template<int RANGE, int NCHUNK, int K>
__device__ void csr_build_seg(const unsigned* __restrict__ slab, const int* __restrict__ offC,
                              const int* __restrict__ btot,
                              int n, int* __restrict__ offs, int* __restrict__ csr,
                              int b, unsigned* stage, int* hist, int* part,
                              ushortT* mstA, ushortT* mlenA, ushortT* sbA){
  constexpr int CPT = (NCHUNK + 255) / 256;
  int tid = threadIdx.x;
  int dlo = b*RANGE;
  int range = n - dlo; if (range > RANGE) range = RANGE; if (range < 0) range = 0;
  int ownT = 0;
  #pragma unroll
  for (int k=0;k<NCOPY;++k) ownT += btot[k*NB + tid];
  part[tid] = ownT;
  __syncthreads();
  for (int st=1; st<256; st<<=1){
    int x = (tid >= st) ? part[tid-st] : 0;
    __syncthreads();
    part[tid] += x;
    __syncthreads();
  }
  int totB = part[b];
  int total = part[NB-1];
  if (b == NB-1 && tid == 0) offs[n] = total;
  __syncthreads();
  int mst[CPT], mlen[CPT];
  int csum = 0;
  #pragma unroll
  for (int k=0;k<CPT;++k){
    int c = tid + k*256;
    int l = 0, s0 = 0;
    if (c < NCHUNK){
      s0 = offC[(size_t)c*257 + b];
      l  = offC[(size_t)c*257 + b + 1] - s0;
    }
    mst[k] = s0; mlen[k] = l; csum += l;
  }
  part[tid] = csum;
  __syncthreads();
  int own2 = csum;
  for (int st=1; st<256; st<<=1){
    int x = (tid >= st) ? part[tid-st] : 0;
    __syncthreads();
    part[tid] += x;
    __syncthreads();
  }
  int cnt = part[NB-1];
  int gb = totB - cnt;
  int sb = part[tid] - own2;
  #pragma unroll
  for (int k=0;k<CPT;++k){
    int c = tid + k*256;
    if (c < NCHUNK){
      mstA[c] = (ushortT)mst[k];
      mlenA[c] = (ushortT)mlen[k];
      sbA[c] = (ushortT)sb;
      sb += mlen[k];
    }
  }
  __syncthreads();
  int wv = tid >> 6, l = tid & 63;
  for (int cb = wv*32; cb < NCHUNK; cb += 128){
    int c = cb + (l >> 1);
    if (c < NCHUNK){
      int len = mlenA[c];
      int half = l & 1;
      if (half*4 < len){
        const unsigned* sg = slab + (size_t)c*2048 + mstA[c];
        int sbc = sbA[c];
        for (int j = half*4; j < len; j += 8){
          unsigned v[4];
          __builtin_memcpy(v, sg + j, 16);
          #pragma unroll
          for (int q=0;q<4;++q) if (j+q < len) stage[sbc+j+q] = v[q];
        }
      }
    }
  }
  __syncthreads();
  for (int t=tid; t<RANGE; t+=256) hist[t] = 0;
  __syncthreads();
  for (int j=tid; j<cnt; j+=256) atomicAdd(&hist[stage[j] & 2047u], 1);
  __syncthreads();
  int s = 0; int loc[K];
  #pragma unroll
  for (int kk=0; kk<K; ++kk){
    int idx = tid*K + kk;
    int v = (idx < RANGE) ? hist[idx] : 0;
    loc[kk] = s; s += v;
  }
  part[tid] = s; __syncthreads();
  int own3 = s;
  for (int st=1; st<256; st<<=1){
    int x = (tid >= st) ? part[tid-st] : 0;
    __syncthreads();
    part[tid] += x;
    __syncthreads();
  }
  int ebase = part[tid] - own3;
  __syncthreads();
  #pragma unroll
  for (int kk=0; kk<K; ++kk){
    int idx = tid*K + kk;
    if (idx < RANGE){
      int ex = ebase + loc[kk];
      if (idx < range) offs[dlo+idx] = gb + ex;
      hist[idx] = ex;
    }
  }
  __syncthreads();
  for (int j=tid; j<cnt; j+=256){
    unsigned p = stage[j];
    int pos = atomicAdd(&hist[p & 2047u], 1);
    csr[gb + pos] = (int)(p >> 11);
  }
}

__global__ __launch_bounds__(256) void k_build_all(
    const unsigned* s0, const int* oc0, const int* bt0, int* offs0, int* csr0,
    const unsigned* s1, const int* oc1, const int* bt1, int* offs1, int* csr1,
    const unsigned* sL, const int* ocL, const int* btL, int* offsL, int* csrL){
  __shared__ unsigned stage[CAP0];
  __shared__ int hist[RANGE0];
  __shared__ int part[256];
  __shared__ ushortT mstA[NCH0];
  __shared__ ushortT mlenA[NCH0];
  __shared__ ushortT sbA[NCH0];
  int b = blockIdx.x;
  if (b < 256)      csr_build_seg<RANGE0,NCH0,2>(s0, oc0, bt0, N_PTS, offs0, csr0, b, stage, hist, part, mstA, mlenA, sbA);
  else if (b < 512) csr_build_seg<RANGE1,NCH1,1>(s1, oc1, bt1, M_CL, offs1, csr1, b-256, stage, hist, part, mstA, mlenA, sbA);
  else              csr_build_seg<RANGE1,NCHL,1>(sL, ocL, btL, M_CL, offsL, csrL, b-512, stage, hist, part, mstA, mlenA, sbA);
}

// ============================ FUSED: wprep (17) + chunk sort (1027) + f1g ============================

__global__ __launch_bounds__(256) void k_bin_f1g(
    WSrc s, ushortT* __restrict__ wt, ushortT* __restrict__ wtc, float* __restrict__ wpp,
    const int* __restrict__ l0e, const int* __restrict__ l1e, const int* __restrict__ labels,
    int* bt0, int* bt1, int* btL,
    unsigned* sl0, unsigned* sl1, unsigned* slL,
    int* oc0, int* oc1, int* ocL,
    const float* __restrict__ features, const float* __restrict__ points,
    const float* __restrict__ centers,
    const float* __restrict__ W, const float* __restrict__ bfe,
    const float* __restrict__ bias2, const float* __restrict__ We,
    float* __restrict__ rel, ushortT* __restrict__ f1b,
    ushortT* __restrict__ gout, int n, int ntiles, int nf1blk)
{
  __shared__ char smem[10240];
  int b = blockIdx.x;
  if (b < 17){
    int slot = b;
    if (slot < 15){
      const float* src = s.p[slot];
      ushortT* dst = wt + slot*4096;
      for (int e=threadIdx.x; e<4096; e+=256){
        int nn = e>>6, p = e&63;
        int kk = (p&3)*16 + (p>>2);
        dst[e] = f2bf(src[kk*64+nn]);
      }
    } else if (slot == 15){
      const float* src = s.p[15];
      for (int e=threadIdx.x; e<1024; e+=256){
        int nn = e>>6, p = e&63;
        int kk = (p&3)*16 + (p>>2);
        wtc[e] = (nn<8) ? f2bf(src[kk*8+nn]) : (ushortT)0;
      }
    } else {
      for (int e=threadIdx.x; e<6*192; e+=256){
        int i = e/192, rem = e - i*192, r = rem>>6, p = rem&63;
        wpp[e] = s.p[16+i][r*64 + ((p&3)*16 + (p>>2))];
      }
    }
    return;
  }
  b -= 17;
  if (b < 1027){
    unsigned* slds = (unsigned*)smem;
    int* hist = (int*)(smem + 8192);
    int* pfx  = (int*)(smem + 9216);
    if (b < 782)      sort_chunk<RANGE0,false>(l0e, E0_N, b,     sl0, oc0, bt0, slds, hist, pfx);
    else if (b < 978) sort_chunk<RANGE1,false>(l1e, E1_N, b-782, sl1, oc1, bt1, slds, hist, pfx);
    else              sort_chunk<RANGE1,true >(labels, N_PTS, b-978, slL, ocL, btL, slds, hist, pfx);
    return;
  }
  // ---- f1g ----
  ushortT* lds = (ushortT*)smem;
  int bb = b - 1027;
  int tid = threadIdx.x;
  int lane = tid & 63, wslot = tid >> 6;
  int quad = lane >> 4, l15 = lane & 15;
  int permL = (lane & 15)*4 + (lane >> 4);
  int r3 = lane/3, c3 = lane - r3*3;
  int gw = (bb*256 + tid) >> 6;
  int nw = (nf1blk*256) >> 6;
  float Wf0=W[0*64+lane], Wf1=W[1*64+lane], Wf2=W[2*64+lane], Wf3=W[3*64+lane];
  float wr0=W[4*64+lane], wr1=W[5*64+lane], wr2=W[6*64+lane];
  float bias=bfe[lane];
  const float* Wk = We + 192;
  auto ldf = [&](int nn, int pbase)->short8{
    short8 r;
    #pragma unroll
    for (int e=0;e<8;++e){
      int p = pbase + e;
      int kk = (p&3)*16 + (p>>2);
      r[e] = (short)f2bf(Wk[kk*64 + nn]);
    }
    return r;
  };
  short8 s0_0 = ldf(l15, quad*8),      s0_1 = ldf(l15, 32+quad*8);
  short8 s1_0 = ldf(16+l15, quad*8),   s1_1 = ldf(16+l15, 32+quad*8);
  short8 s2_0 = ldf(32+l15, quad*8),   s2_1 = ldf(32+l15, 32+quad*8);
  short8 s3_0 = ldf(48+l15, quad*8),   s3_1 = ldf(48+l15, 32+quad*8);
  float eb0 = bias2[l15], eb1 = bias2[16+l15], eb2 = bias2[32+l15], eb3 = bias2[48+l15];
  float e0c0=We[0*64+l15], e0c1=We[0*64+16+l15], e0c2=We[0*64+32+l15], e0c3=We[0*64+48+l15];
  float e1c0=We[1*64+l15], e1c1=We[1*64+16+l15], e1c2=We[1*64+32+l15], e1c3=We[1*64+48+l15];
  float e2c0=We[2*64+l15], e2c1=We[2*64+16+l15], e2c2=We[2*64+32+l15], e2c3=We[2*64+48+l15];

  for (int t=gw; t<ntiles; t+=nw){
    int i0 = t*16;
    int lab16 = labels[min(i0 + (lane & 15), n-1)];
    float fv  = features[(size_t)min(i0 + (lane>>2), n-1)*4 + (lane & 3)];
    int lb = __shfl(lab16, (r3 < 16) ? r3 : 0, 64);
    float pv = 0.f, relv = 0.f;
    if (lane < 48){
      int rowp = i0 + r3;
      int rc = (rowp < n) ? rowp : (n-1);
      pv = points[(size_t)rc*3 + c3];
      float cv = centers[(size_t)lb*3 + c3];
      relv = pv - cv;
      if (rowp < n) rel[(size_t)rowp*3 + c3] = relv;
    }
    #pragma unroll
    for (int r=0;r<16;++r){
      float rx = __shfl(relv, 3*r+0, 64);
      float ry = __shfl(relv, 3*r+1, 64);
      float rz = __shfl(relv, 3*r+2, 64);
      float f0 = __shfl(fv, 4*r+0, 64);
      float f1 = __shfl(fv, 4*r+1, 64);
      float f2 = __shfl(fv, 4*r+2, 64);
      float f3 = __shfl(fv, 4*r+3, 64);
      float acc = bias + wr0*rx + wr1*ry + wr2*rz;
      acc += f0*Wf0 + f1*Wf1;
      acc += f2*Wf2 + f3*Wf3;
      acc = fmaxf(acc, 0.f);
      ushortT ab = f2bf(acc);
      int row = i0 + r;
      if (row < n) f1b[(size_t)row*64 + permL] = ab;
      lds[wslot*(16*LSTR) + r*LSTR + permL] = ab;
    }
    __builtin_amdgcn_wave_barrier();
    const ushortT* lp = lds + wslot*(16*LSTR) + l15*LSTR + quad*8;
    short8 sa0 = *(const short8*)(lp);
    short8 sa1 = *(const short8*)(lp + 32);
    __builtin_amdgcn_wave_barrier();
    v4f ec0 = {0.f,0.f,0.f,0.f}, ec1 = ec0, ec2 = ec0, ec3 = ec0;
    ec0 = __builtin_amdgcn_mfma_f32_16x16x32_bf16(sa0, s0_0, ec0, 0,0,0);
    ec1 = __builtin_amdgcn_mfma_f32_16x16x32_bf16(sa0, s1_0, ec1, 0,0,0);
    ec2 = __builtin_amdgcn_mfma_f32_16x16x32_bf16(sa0, s2_0, ec2, 0,0,0);
    ec3 = __builtin_amdgcn_mfma_f32_16x16x32_bf16(sa0, s3_0, ec3, 0,0,0);
    ec0 = __builtin_amdgcn_mfma_f32_16x16x32_bf16(sa1, s0_1, ec0, 0,0,0);
    ec1 = __builtin_amdgcn_mfma_f32_16x16x32_bf16(sa1, s1_1, ec1, 0,0,0);
    ec2 = __builtin_amdgcn_mfma_f32_16x16x32_bf16(sa1, s2_1, ec2, 0,0,0);
    ec3 = __builtin_amdgcn_mfma_f32_16x16x32_bf16(sa1, s3_1, ec3, 0,0,0);
    #pragma unroll
    for (int r=0;r<4;++r){
      int row = i0 + quad*4 + r;
      if (row < n){
        int rr4 = quad*4 + r;
        float vx = __shfl(pv, 3*rr4+0, 64);
        float vy = __shfl(pv, 3*rr4+1, 64);
        float vz = __shfl(pv, 3*rr4+2, 64);
        float g0 = ec0[r] + eb0 + vx*e0c0 + vy*e1c0 + vz*e2c0;
        float g1 = ec1[r] + eb1 + vx*e0c1 + vy*e1c1 + vz*e2c1;
        float g2 = ec2[r] + eb2 + vx*e0c2 + vy*e1c2 + vz*e2c2;
        float g3 = ec3[r] + eb3 + vx*e0c3 + vy*e1c3 + vz*e2c3;
        s4v o; o.x=(short)f2h(g0); o.y=(short)f2h(g1); o.z=(short)f2h(g2); o.w=(short)f2h(g3);
        *(s4v*)(gout + (size_t)row*64 + l15*4) = o;
      }
    }
  }
}

// ============================ shared GEMM body (device) ============================

template<bool RELU, int NRES, bool USEREL, bool GATHER, bool OUT16, bool F16O, int EMODE, bool ERELU>
__device__ void gemm_body(
    const ushortT* __restrict__ A, const ushortT* __restrict__ Wt,
    const float* __restrict__ bias, const float* __restrict__ Wr,
    const float* __restrict__ rel, const int* __restrict__ gidx,
    const ushortT* __restrict__ r1, const ushortT* __restrict__ r2,
    ushortT* __restrict__ out16,
    const ushortT* __restrict__ Wt2, const float* __restrict__ bias2,
    const float* __restrict__ Wr2, const float* __restrict__ vec2,
    void* __restrict__ eout,
    int n, int ntiles, int gw, int nw, ushortT* lds)
{
  int tid = threadIdx.x;
  int lane = tid & 63, wslot = tid >> 6;
  int quad = lane >> 4, l15 = lane & 15;
  int r3 = lane/3, c3 = lane - r3*3;

  short8 bfr0_0 = *(const short8*)(Wt + ( 0 + l15)*64 +  0 + quad*8);
  short8 bfr0_1 = *(const short8*)(Wt + ( 0 + l15)*64 + 32 + quad*8);
  short8 bfr1_0 = *(const short8*)(Wt + (16 + l15)*64 +  0 + quad*8);
  short8 bfr1_1 = *(const short8*)(Wt + (16 + l15)*64 + 32 + quad*8);
  short8 bfr2_0 = *(const short8*)(Wt + (32 + l15)*64 +  0 + quad*8);
  short8 bfr2_1 = *(const short8*)(Wt + (32 + l15)*64 + 32 + quad*8);
  short8 bfr3_0 = *(const short8*)(Wt + (48 + l15)*64 +  0 + quad*8);
  short8 bfr3_1 = *(const short8*)(Wt + (48 + l15)*64 + 32 + quad*8);
  float bs0 = bias[ 0 + l15], bs1 = bias[16 + l15];
  float bs2 = bias[32 + l15], bs3 = bias[48 + l15];
  float w0c0=0,w0c1=0,w0c2=0,w0c3=0, w1c0=0,w1c1=0,w1c2=0,w1c3=0, w2c0=0,w2c1=0,w2c2=0,w2c3=0;
  if (USEREL){
    w0c0=Wr[0*64+l15]; w0c1=Wr[0*64+16+l15]; w0c2=Wr[0*64+32+l15]; w0c3=Wr[0*64+48+l15];
    w1c0=Wr[1*64+l15]; w1c1=Wr[1*64+16+l15]; w1c2=Wr[1*64+32+l15]; w1c3=Wr[1*64+48+l15];
    w2c0=Wr[2*64+l15]; w2c1=Wr[2*64+16+l15]; w2c2=Wr[2*64+32+l15]; w2c3=Wr[2*64+48+l15];
  }

  short8 s0_0{}, s0_1{}, s1_0{}, s1_1{}, s2_0{}, s2_1{}, s3_0{}, s3_1{};
  float eb0=0, eb1=0, eb2=0, eb3=0;
  float e0c0=0,e0c1=0,e0c2=0,e0c3=0, e1c0=0,e1c1=0,e1c2=0,e1c3=0, e2c0=0,e2c1=0,e2c2=0,e2c3=0;
  float ebias_c = 0.f;
  if (EMODE == 1){
    s0_0 = *(const short8*)(Wt2 + ( 0 + l15)*64 +  0 + quad*8);
    s0_1 = *(const short8*)(Wt2 + ( 0 + l15)*64 + 32 + quad*8);
    s1_0 = *(const short8*)(Wt2 + (16 + l15)*64 +  0 + quad*8);
    s1_1 = *(const short8*)(Wt2 + (16 + l15)*64 + 32 + quad*8);
    s2_0 = *(const short8*)(Wt2 + (32 + l15)*64 +  0 + quad*8);
    s2_1 = *(const short8*)(Wt2 + (32 + l15)*64 + 32 + quad*8);
    s3_0 = *(const short8*)(Wt2 + (48 + l15)*64 +  0 + quad*8);
    s3_1 = *(const short8*)(Wt2 + (48 + l15)*64 + 32 + quad*8);
    eb0 = bias2[l15]; eb1 = bias2[16+l15]; eb2 = bias2[32+l15]; eb3 = bias2[48+l15];
    e0c0=Wr2[0*64+l15]; e0c1=Wr2[0*64+16+l15]; e0c2=Wr2[0*64+32+l15]; e0c3=Wr2[0*64+48+l15];
    e1c0=Wr2[1*64+l15]; e1c1=Wr2[1*64+16+l15]; e1c2=Wr2[1*64+32+l15]; e1c3=Wr2[1*64+48+l15];
    e2c0=Wr2[2*64+l15]; e2c1=Wr2[2*64+16+l15]; e2c2=Wr2[2*64+32+l15]; e2c3=Wr2[2*64+48+l15];
  } else if (EMODE == 2){
    s0_0 = *(const short8*)(Wt2 + l15*64 +  0 + quad*8);
    s0_1 = *(const short8*)(Wt2 + l15*64 + 32 + quad*8);
    ebias_c = (l15 < 8) ? bias2[l15] : 0.f;
  }

  for (int t=gw; t<ntiles; t+=nw){
    int i0 = t*16;
    int rowA = i0 + l15; if (rowA >= n) rowA = n-1;
    if (GATHER) rowA = gidx[rowA];
    const ushortT* ap = A + (size_t)rowA*64 + quad*8;
    short8 a0 = *(const short8*)(ap);
    short8 a1 = *(const short8*)(ap + 32);
    float relL = 0.f;
    if (USEREL && lane < 48){
      int rc = i0 + r3; if (rc >= n) rc = n-1;
      relL = rel[(size_t)rc*3 + c3];
    }
    v4f ac0 = {0.f,0.f,0.f,0.f}, ac1 = ac0, ac2 = ac0, ac3 = ac0;
    ac0 = __builtin_amdgcn_mfma_f32_16x16x32_bf16(a0, bfr0_0, ac0, 0,0,0);
    ac1 = __builtin_amdgcn_mfma_f32_16x16x32_bf16(a0, bfr1_0, ac1, 0,0,0);
    ac2 = __builtin_amdgcn_mfma_f32_16x16x32_bf16(a0, bfr2_0, ac2, 0,0,0);
    ac3 = __builtin_amdgcn_mfma_f32_16x16x32_bf16(a0, bfr3_0, ac3, 0,0,0);
    ac0 = __builtin_amdgcn_mfma_f32_16x16x32_bf16(a1, bfr0_1, ac0, 0,0,0);
    ac1 = __builtin_amdgcn_mfma_f32_16x16x32_bf16(a1, bfr1_1, ac1, 0,0,0);
    ac2 = __builtin_amdgcn_mfma_f32_16x16x32_bf16(a1, bfr2_1, ac2, 0,0,0);
    ac3 = __builtin_amdgcn_mfma_f32_16x16x32_bf16(a1, bfr3_1, ac3, 0,0,0);

    #pragma unroll
    for (int r=0;r<4;++r){
      int row = i0 + quad*4 + r;
      bool rowok = (row < n);
      float v0 = ac0[r] + bs0, v1 = ac1[r] + bs1, v2 = ac2[r] + bs2, v3 = ac3[r] + bs3;
      if (USEREL){
        int rr4 = quad*4 + r;
        float rx = __shfl(relL, 3*rr4+0, 64);
        float ry = __shfl(relL, 3*rr4+1, 64);
        float rz = __shfl(relL, 3*rr4+2, 64);
        v0 += rx*w0c0 + ry*w1c0 + rz*w2c0;
        v1 += rx*w0c1 + ry*w1c1 + rz*w2c1;
        v2 += rx*w0c2 + ry*w1c2 + rz*w2c2;
        v3 += rx*w0c3 + ry*w1c3 + rz*w2c3;
      }
      if (RELU){ v0=fmaxf(v0,0.f); v1=fmaxf(v1,0.f); v2=fmaxf(v2,0.f); v3=fmaxf(v3,0.f); }
      size_t pb = (size_t)row*64 + l15*4;
      if (rowok){
        if (NRES>=1){
          s4v rv = *(const s4v*)(r1 + pb);
          v0 += bf2f((ushortT)rv.x); v1 += bf2f((ushortT)rv.y);
          v2 += bf2f((ushortT)rv.z); v3 += bf2f((ushortT)rv.w);
        }
        if (NRES>=2){
          s4v rv = *(const s4v*)(r2 + pb);
          v0 += bf2f((ushortT)rv.x); v1 += bf2f((ushortT)rv.y);
          v2 += bf2f((ushortT)rv.z); v3 += bf2f((ushortT)rv.w);
        }
        if (OUT16){
          s4v o;
          if (F16O){ o.x=(short)f2h(v0); o.y=(short)f2h(v1); o.z=(short)f2h(v2); o.w=(short)f2h(v3); }
          else     { o.x=(short)f2bf(v0); o.y=(short)f2bf(v1); o.z=(short)f2bf(v2); o.w=(short)f2bf(v3); }
          *(s4v*)(out16 + pb) = o;
        }
      }
      if (EMODE > 0){
        int lb = wslot*(16*LSTR) + (quad*4+r)*LSTR + l15*4;
        s4v o; o.x=(short)f2bf(v0); o.y=(short)f2bf(v1); o.z=(short)f2bf(v2); o.w=(short)f2bf(v3);
        *(s4v*)(lds + lb) = o;
      }
    }

    if (EMODE > 0){
      __builtin_amdgcn_wave_barrier();
      const ushortT* lp = lds + wslot*(16*LSTR) + l15*LSTR + quad*8;
      short8 sa0 = *(const short8*)(lp);
      short8 sa1 = *(const short8*)(lp + 32);
      __builtin_amdgcn_wave_barrier();
      if (EMODE == 1){
        float posv = 0.f;
        if (lane < 48){
          int rc = i0 + r3; if (rc >= n) rc = n-1;
          posv = vec2[(size_t)rc*3 + c3];
        }
        v4f ec0 = {0.f,0.f,0.f,0.f}, ec1 = ec0, ec2 = ec0, ec3 = ec0;
        ec0 = __builtin_amdgcn_mfma_f32_16x16x32_bf16(sa0, s0_0, ec0, 0,0,0);
        ec1 = __builtin_amdgcn_mfma_f32_16x16x32_bf16(sa0, s1_0, ec1, 0,0,0);
        ec2 = __builtin_amdgcn_mfma_f32_16x16x32_bf16(sa0, s2_0, ec2, 0,0,0);
        ec3 = __builtin_amdgcn_mfma_f32_16x16x32_bf16(sa0, s3_0, ec3, 0,0,0);
        ec0 = __builtin_amdgcn_mfma_f32_16x16x32_bf16(sa1, s0_1, ec0, 0,0,0);
        ec1 = __builtin_amdgcn_mfma_f32_16x16x32_bf16(sa1, s1_1, ec1, 0,0,0);
        ec2 = __builtin_amdgcn_mfma_f32_16x16x32_bf16(sa1, s2_1, ec2, 0,0,0);
        ec3 = __builtin_amdgcn_mfma_f32_16x16x32_bf16(sa1, s3_1, ec3, 0,0,0);
        ushortT* eo = (ushortT*)eout;
        #pragma unroll
        for (int r=0;r<4;++r){
          int row = i0 + quad*4 + r;
          if (row < n){
            int rr4 = quad*4 + r;
            float vx = __shfl(posv, 3*rr4+0, 64);
            float vy = __shfl(posv, 3*rr4+1, 64);
            float vz = __shfl(posv, 3*rr4+2, 64);
            float g0 = ec0[r] + eb0 + vx*e0c0 + vy*e1c0 + vz*e2c0;
            float g1 = ec1[r] + eb1 + vx*e0c1 + vy*e1c1 + vz*e2c1;
            float g2 = ec2[r] + eb2 + vx*e0c2 + vy*e1c2 + vz*e2c2;
            float g3 = ec3[r] + eb3 + vx*e0c3 + vy*e1c3 + vz*e2c3;
            if (ERELU){ g0=fmaxf(g0,0.f); g1=fmaxf(g1,0.f); g2=fmaxf(g2,0.f); g3=fmaxf(g3,0.f); }
            s4v o; o.x=(short)f2h(g0); o.y=(short)f2h(g1); o.z=(short)f2h(g2); o.w=(short)f2h(g3);
            *(s4v*)(eo + (size_t)row*64 + l15*4) = o;
          }
        }
      } else {
        v4f ec = {0.f,0.f,0.f,0.f};
        ec = __builtin_amdgcn_mfma_f32_16x16x32_bf16(sa0, s0_0, ec, 0,0,0);
        ec = __builtin_amdgcn_mfma_f32_16x16x32_bf16(sa1, s0_1, ec, 0,0,0);
        if (l15 < 8){
          float* eo = (float*)eout;
          #pragma unroll
          for (int r=0;r<4;++r){
            int row = i0 + quad*4 + r;
            if (row < n) eo[(size_t)row*8 + l15] = ec[r] + ebias_c;
          }
        }
      }
    }
  }
}

template<bool RELU, int NRES, bool USEREL, bool GATHER, bool OUT16, bool F16O, int EMODE, bool ERELU>
__global__ __launch_bounds__(256) void k_gemm(
    const ushortT* __restrict__ A, const ushortT* __restrict__ Wt,
    const float* __restrict__ bias, const float* __restrict__ Wr,
    const float* __restrict__ rel, const int* __restrict__ gidx,
    const ushortT* __restrict__ r1, const ushortT* __restrict__ r2,
    ushortT* __restrict__ out16,
    const ushortT* __restrict__ Wt2, const float* __restrict__ bias2,
    const float* __restrict__ Wr2, const float* __restrict__ vec2,
    void* __restrict__ eout,
    int n, int ntiles)
{
  constexpr int LDSZ = (EMODE>0) ? 4*16*LSTR : 4;
  __shared__ ushortT lds[LDSZ];
  int gw = (blockIdx.x*256 + threadIdx.x) >> 6;
  int nw = (gridDim.x*256) >> 6;
  gemm_body<RELU,NRES,USEREL,GATHER,OUT16,F16O,EMODE,ERELU>(
      A, Wt, bias, Wr, rel, gidx, r1, r2, out16, Wt2, bias2, Wr2, vec2, eout,
      n, ntiles, gw, nw, lds);
}

// ============================ shared edge-agg body (device) ============================

__device__ void agg_body(const int* __restrict__ offs, const int* __restrict__ csr,
                         const float* __restrict__ pos, const ushortT* __restrict__ g,
                         const float* __restrict__ Wp, ushortT* __restrict__ agg, int n,
                         int gw, int nw){
  int lane = threadIdx.x & 63;
  int grp = lane >> 3, d8 = lane & 7;
  int gbase = lane & 56;
  const u4v* g4 = (const u4v*)g;
  float2 w0[4], w1[4], w2[4];
  #pragma unroll
  for (int q=0;q<4;++q){
    w0[q] = *(const float2*)(Wp + 0*64 + d8*8 + 2*q);
    w1[q] = *(const float2*)(Wp + 1*64 + d8*8 + 2*q);
    w2[q] = *(const float2*)(Wp + 2*64 + d8*8 + 2*q);
  }
  const h2 NEGBIG = {(_Float16)-60000.f, (_Float16)-60000.f};
  int n8 = (n+7) >> 3;
  for (int ii=gw; ii<n8; ii+=nw){
    int i0 = ii*8;
    int ig = i0 + grp; bool ok = ig < n; if (!ok) ig = n-1;
    int b = offs[ig], e = offs[ig+1];
    int cnt = e - b, c1 = cnt - 1;
    int mx = cnt;
    mx = max(mx, __shfl_xor(mx, 8, 64));
    mx = max(mx, __shfl_xor(mx, 16, 64));
    mx = max(mx, __shfl_xor(mx, 32, 64));
    h2 m0=NEGBIG, m1=NEGBIG, m2=NEGBIG, m3=NEGBIG;
    for (int J=0; J<mx; J+=8){
      if (J < cnt){
        int sv = csr[b + min(J + d8, c1)];
        #pragma unroll
        for (int jj=0; jj<8; ++jj){
          int s = __shfl(sv, gbase + jj, 64);
          u4v u = g4[(size_t)s*8 + d8];
          m0 = pkmax(m0, u2h(u.x));
          m1 = pkmax(m1, u2h(u.y));
          m2 = pkmax(m2, u2h(u.z));
          m3 = pkmax(m3, u2h(u.w));
        }
      }
    }
    float px = pos[ig*3+0], py = pos[ig*3+1], pz = pos[ig*3+2];
    u4v outv;
    {
      float sA = w0[0].x*px + w1[0].x*py + w2[0].x*pz;
      float sB = w0[0].y*px + w1[0].y*py + w2[0].y*pz;
      outv.x = (unsigned)f2bf(fmaxf((float)m0.x - sA, 0.f)) |
               ((unsigned)f2bf(fmaxf((float)m0.y - sB, 0.f)) << 16);
    }
    {
      float sA = w0[1].x*px + w1[1].x*py + w2[1].x*pz;
      float sB = w0[1].y*px + w1[1].y*py + w2[1].y*pz;
      outv.y = (unsigned)f2bf(fmaxf((float)m1.x - sA, 0.f)) |
               ((unsigned)f2bf(fmaxf((float)m1.y - sB, 0.f)) << 16);
    }
    {
      float sA = w0[2].x*px + w1[2].x*py + w2[2].x*pz;
      float sB = w0[2].y*px + w1[2].y*py + w2[2].y*pz;
      outv.z = (unsigned)f2bf(fmaxf((float)m2.x - sA, 0.f)) |
               ((unsigned)f2bf(fmaxf((float)m2.y - sB, 0.f)) << 16);
    }
    {
      float sA = w0[3].x*px + w1[3].x*py + w2[3].x*pz;
      float sB = w0[3].y*px + w1[3].y*py + w2[3].y*pz;
      outv.w = (unsigned)f2bf(fmaxf((float)m3.x - sA, 0.f)) |
               ((unsigned)f2bf(fmaxf((float)m3.y - sB, 0.f)) << 16);
    }
    if (ok) ((u4v*)agg)[(size_t)ig*8 + d8] = outv;
  }
}

__global__ __launch_bounds__(256) void k_edge_agg(const int* __restrict__ offs, const int* __restrict__ csr,
                                                  const float* __restrict__ pos, const ushortT* __restrict__ g,
                                                  const float* __restrict__ Wp, ushortT* __restrict__ agg, int n){
  int gw = (blockIdx.x*256 + threadIdx.x) >> 6;
  int nw = (gridDim.x*256) >> 6;
  agg_body(offs, csr, pos, g, Wp, agg, n, gw, nw);
}

// ============================ seg-sum body (device) ============================

__device__ void seg_body(const int* __restrict__ offs, const int* __restrict__ csr,
                         const ushortT* __restrict__ h, ushortT* __restrict__ c, int m,
                         int wv0, int nwv){
  int lane = threadIdx.x & 63;
  for (int wv = wv0; wv < m; wv += nwv){
    int b = offs[wv], e = offs[wv+1];
    float acc = 0.f;
    for (int k=b; k<e; ++k){
      int i = csr[k];
      acc += h2f(h[(size_t)i*64+lane]);
    }
    c[(size_t)wv*64+lane] = f2bf(acc);
  }
}

// ============================ fused M-cluster chain (one dispatch, grid barriers) ============================
// grid = 256 blocks (<= 256 CUs -> all co-resident; software barrier is safe).
// seg -> bar -> gemmM0(f3+cg0') -> bar -> aggM0 -> bar -> gemmM1(f4+cg1') -> bar
//     -> aggM1 -> bar -> gemmM2(f4_1)

#define MCH_BLK 256

__global__ __launch_bounds__(256) void k_mchain(
    const int* __restrict__ offsL, const int* __restrict__ csrL,
    const ushortT* __restrict__ gbuf, ushortT* __restrict__ cb_b,
    const ushortT* __restrict__ wt, const float* __restrict__ b_m2,
    const float* __restrict__ gbe, const float* __restrict__ gbu,
    const float* __restrict__ gWe, const float* __restrict__ centers,
    const int* __restrict__ offs1, const int* __restrict__ csr1,
    const float* __restrict__ wpp,
    ushortT* __restrict__ cg_b, ushortT* __restrict__ cagg_b,
    ushortT* __restrict__ UF3, ushortT* __restrict__ UF4, ushortT* __restrict__ f41_b,
    int* __restrict__ bar, int ntM)
{
  __shared__ ushortT lds[4*16*LSTR];
  int gw = (blockIdx.x*256 + threadIdx.x) >> 6;
  int nw = (MCH_BLK*256) >> 6;

  // A: c = segsum(h)
  seg_body(offsL, csrL, gbuf, cb_b, M_CL, gw, nw);
  gridbar(bar+0, MCH_BLK);
  // B: f3 -> UF3, cg0' -> cg_b
  gemm_body<true,0,false,false,true,false,1,false>(cb_b, wt+4*4096, b_m2,
      nullptr, nullptr, nullptr, nullptr, nullptr, UF3,
      wt+13*4096, gbe+0, gWe+0*4288, centers, cg_b, M_CL, ntM, gw, nw, lds);
  gridbar(bar+1, MCH_BLK);
  // C: aggM0 -> cagg_b
  agg_body(offs1, csr1, centers, cg_b, wpp+4*192, cagg_b, M_CL, gw, nw);
  gridbar(bar+2, MCH_BLK);
  // D: f4 -> UF4, cg1' -> cg_b
  gemm_body<true,1,false,false,true,false,1,false>(cagg_b, wt+5*4096, gbu+0,
      nullptr, nullptr, nullptr, UF3, nullptr, UF4,
      wt+14*4096, gbe+64, gWe+1*4288, centers, cg_b, M_CL, ntM, gw, nw, lds);
  gridbar(bar+3, MCH_BLK);
  // E: aggM1 -> cagg_b
  agg_body(offs1, csr1, centers, cg_b, wpp+5*192, cagg_b, M_CL, gw, nw);
  gridbar(bar+4, MCH_BLK);
  // F: f4_1 -> f41_b
  gemm_body<true,1,false,false,true,false,0,false>(cagg_b, wt+6*4096, gbu+64,
      nullptr, nullptr, nullptr, UF4, nullptr, f41_b,
      nullptr, nullptr, nullptr, nullptr, nullptr, M_CL, ntM, gw, nw, lds);
}

// ============================ host launcher ============================

extern "C" void kernel_launch(void* const* d_in, const int* in_sizes, int n_in,
                              void* d_out, int out_size, void* d_ws, size_t ws_size,
                              hipStream_t stream){
  const float* features = (const float*)d_in[0];
  const float* points   = (const float*)d_in[1];
  const float* centers  = (const float*)d_in[2];
  const int*   l0e      = (const int*)d_in[3];
  const int*   l1e      = (const int*)d_in[4];
  const int*   labels   = (const int*)d_in[5];
  const float* W_fe = (const float*)d_in[6];
  const float* b_fe = (const float*)d_in[7];
  const float* mWe  = (const float*)d_in[8];
  const float* mbe  = (const float*)d_in[9];
  const float* mWu  = (const float*)d_in[10];
  const float* mbu  = (const float*)d_in[11];
  const float* W_m1 = (const float*)d_in[12];
  const float* b_m1 = (const float*)d_in[13];
  const float* W_m2 = (const float*)d_in[14];
  const float* b_m2 = (const float*)d_in[15];
  const float* gWe  = (const float*)d_in[16];
  const float* gbe  = (const float*)d_in[17];
  const float* gWu  = (const float*)d_in[18];
  const float* gbu  = (const float*)d_in[19];
  const float* W_l  = (const float*)d_in[20];
  const float* b_l  = (const float*)d_in[21];
  const float* W_c  = (const float*)d_in[22];
  const float* b_c  = (const float*)d_in[23];
  float* out = (float*)d_out;

  char* w = (char*)d_ws;
  size_t off = 0;
  auto alloc = [&](size_t bytes)->void*{
    void* p = (void*)(w + off);
    off = (off + bytes + 255) & ~(size_t)255;
    return p;
  };
  float* rel  = (float*)alloc((size_t)N_PTS*3*4);
  ushortT* UF1 = (ushortT*)alloc((size_t)N_PTS*64*2);
  ushortT* UF2 = (ushortT*)alloc((size_t)N_PTS*64*2);
  ushortT* UF21= (ushortT*)alloc((size_t)N_PTS*64*2);
  ushortT* UF5 = (ushortT*)alloc((size_t)N_PTS*64*2);
  ushortT* UF6 = (ushortT*)alloc((size_t)N_PTS*64*2);
  ushortT* gbuf= (ushortT*)alloc((size_t)N_PTS*64*2);
  ushortT* abuf= (ushortT*)alloc((size_t)N_PTS*64*2);
  ushortT* cb_b= (ushortT*)alloc((size_t)M_CL*64*2);
  ushortT* UF3 = (ushortT*)alloc((size_t)M_CL*64*2);
  ushortT* UF4 = (ushortT*)alloc((size_t)M_CL*64*2);
  ushortT* cg_b= (ushortT*)alloc((size_t)M_CL*64*2);
  ushortT* cagg_b = (ushortT*)alloc((size_t)M_CL*64*2);
  ushortT* f41_b  = (ushortT*)alloc((size_t)M_CL*64*2);
  ushortT* wt  = (ushortT*)alloc((size_t)15*4096*2);
  ushortT* wtc = (ushortT*)alloc((size_t)1024*2);
  float* wpp = (float*)alloc((size_t)6*192*4);
  int* offs0 = (int*)alloc((size_t)(N_PTS+1)*4);
  int* csr0  = (int*)alloc((size_t)E0_N*4);
  int* offs1 = (int*)alloc((size_t)(M_CL+1)*4);
  int* csr1  = (int*)alloc((size_t)E1_N*4);
  int* offsL = (int*)alloc((size_t)(M_CL+1)*4);
  int* csrL  = (int*)alloc((size_t)N_PTS*4);
  unsigned* slab0 = (unsigned*)alloc((size_t)NCH0*2048*4);
  unsigned* slab1 = (unsigned*)alloc((size_t)NCH1*2048*4);
  unsigned* slabL = (unsigned*)alloc((size_t)NCHL*2048*4);
  int* offC0 = (int*)alloc((size_t)NCH0*257*4);
  int* offC1 = (int*)alloc((size_t)NCH1*257*4);
  int* offCL = (int*)alloc((size_t)NCHL*257*4);
  int* btotA = (int*)alloc((size_t)(3*NCOPY*NB + 64)*4);   // + barrier counters
  int* btot0 = btotA;
  int* btot1 = btotA + NCOPY*NB;
  int* btotL = btotA + 2*NCOPY*NB;
  int* bar   = btotA + 3*NCOPY*NB;
  (void)ws_size; (void)in_sizes; (void)n_in; (void)out_size;

  const int NT_N = (N_PTS+15)/16;
  const int NT_M = (M_CL +15)/16;
  const int GBG_N = 1563;
  const int GB_N  = 3125;
  const int GB_BIN = 17 + 1027;

  WSrc ws{};
  ws.p[0]=mWu+0*4096; ws.p[1]=mWu+1*4096; ws.p[2]=mWu+2*4096; ws.p[3]=mWu+3*4096;
  ws.p[4]=W_m2; ws.p[5]=gWu+0*4096; ws.p[6]=gWu+1*4096;
  ws.p[7]=mWe+0*4288+192; ws.p[8]=mWe+1*4288+192; ws.p[9]=mWe+2*4288+192; ws.p[10]=mWe+3*4288+192;
  ws.p[11]=W_m1; ws.p[12]=W_l; ws.p[13]=gWe+0*4288+192; ws.p[14]=gWe+1*4288+192;
  ws.p[15]=W_c;
  ws.p[16]=mWe+0*4288; ws.p[17]=mWe+1*4288; ws.p[18]=mWe+2*4288; ws.p[19]=mWe+3*4288;
  ws.p[20]=gWe+0*4288; ws.p[21]=gWe+1*4288;

  hipMemsetAsync(btotA, 0, (size_t)(3*NCOPY*NB + 64)*4, stream);
  k_bin_f1g<<<GB_BIN + GBG_N, 256, 0, stream>>>(ws, wt, wtc, wpp,
      l0e, l1e, labels, btot0, btot1, btotL,
      slab0, slab1, slabL, offC0, offC1, offCL,
      features, points, centers, W_fe, b_fe, mbe, mWe,
      rel, UF1, gbuf, N_PTS, NT_N, GBG_N);
  k_build_all<<<768, 256, 0, stream>>>(slab0, offC0, btot0, offs0, csr0,
                                       slab1, offC1, btot1, offs1, csr1,
                                       slabL, offCL, btotL, offsL, csrL);

  // ---- layer0: agg -> FUSED [f2 -> UF2] + [g1' -> gbuf] ----
  k_edge_agg<<<GB_N,256,0,stream>>>(offs0, csr0, points, gbuf, wpp+0*192, abuf, N_PTS);
  k_gemm<true,1,false,false,true,false,1,false><<<GBG_N,256,0,stream>>>(abuf, wt+0*4096, mbu+0,
      nullptr, nullptr, nullptr, UF1, nullptr, UF2,
      wt+8*4096, mbe+64, mWe+1*4288, points, gbuf, N_PTS, NT_N);
  // ---- layer1: agg -> FUSED [f2_1 -> UF21] + [h -> gbuf] ----
  k_edge_agg<<<GB_N,256,0,stream>>>(offs0, csr0, points, gbuf, wpp+1*192, abuf, N_PTS);
  k_gemm<true,1,false,false,true,false,1,true><<<GBG_N,256,0,stream>>>(abuf, wt+1*4096, mbu+64,
      nullptr, nullptr, nullptr, UF2, nullptr, UF21,
      wt+11*4096, b_m1, W_m1+4096, rel, gbuf, N_PTS, NT_N);
  // ---- FUSED M-cluster chain: seg + f3/cg0 + aggM0 + f4/cg1 + aggM1 + f4_1 ----
  k_mchain<<<MCH_BLK,256,0,stream>>>(offsL, csrL, gbuf, cb_b,
      wt, b_m2, gbe, gbu, gWe, centers,
      offs1, csr1, wpp, cg_b, cagg_b, UF3, UF4, f41_b, bar, NT_M);
  // ---- FUSED [f5 -> UF5] + [g2' -> gbuf] ----
  k_gemm<true,0,true,true,true,false,1,false><<<GBG_N,256,0,stream>>>(f41_b, wt+12*4096, b_l,
      W_l+4096, rel, labels, nullptr, nullptr, UF5,
      wt+9*4096, mbe+128, mWe+2*4288, points, gbuf, N_PTS, NT_N);
  // ---- layer2: agg -> FUSED [f6 = relu+f5+f2_1 -> UF6] + [g3' -> gbuf] ----
  k_edge_agg<<<GB_N,256,0,stream>>>(offs0, csr0, points, gbuf, wpp+2*192, abuf, N_PTS);
  k_gemm<true,2,false,false,true,false,1,false><<<GBG_N,256,0,stream>>>(abuf, wt+2*4096, mbu+128,
      nullptr, nullptr, nullptr, UF5, UF21, UF6,
      wt+10*4096, mbe+192, mWe+3*4288, points, gbuf, N_PTS, NT_N);
  // ---- layer3: agg -> FUSED [final = relu+f6+f2] + [out = final@W_c + b_c] ----
  k_edge_agg<<<GB_N,256,0,stream>>>(offs0, csr0, points, gbuf, wpp+3*192, abuf, N_PTS);
  k_gemm<true,2,false,false,false,false,2,false><<<GBG_N,256,0,stream>>>(abuf, wt+3*4096, mbu+192,
      nullptr, nullptr, nullptr, UF6, UF2, nullptr,
      wtc, b_c, nullptr, nullptr, out, N_PTS, NT_N);
}

// Round 11
// 449.032 us; speedup vs baseline: 1.3424x; 1.3424x over previous
//
#include <hip/hip_runtime.h>

// R11 = exact revert to R9 (best measured: 451.1 µs). R10's grid-barrier fused
// M-chain regressed 195 µs: TLP collapse (12500 -> 1024 waves on latency-bound
// seg/agg phases) + contended spin-barrier RMW (the same same-address-atomic
// wall measured in R4-R8). Separate small dispatches are the right structure
// for the M-cluster chain.
// Carried state: sorted slabs + striped btot[32][256], cooperative build
// gather, fused wprep+bin+f1g (one dispatch), permuted column activations,
// K-permuted weights, R0-shape edge agg (128B/edge, measured L3 roofline).

#define N_PTS   100000
#define M_CL    12500
#define E0_N    1600000
#define E1_N    400000

#define NB      256
#define NCOPY   32
#define RANGE0  391
#define RANGE1  49
#define NCH0    782
#define NCH1    196
#define NCHL    49
#define CAP0    7168
#define CAP1    2048
#define CAPL    768

#define LSTR    72           // LDS row stride (shorts): 144 B

typedef unsigned short ushortT;
typedef short  short8 __attribute__((ext_vector_type(8)));
typedef short  s4v    __attribute__((ext_vector_type(4)));
typedef float  v4f    __attribute__((ext_vector_type(4)));
typedef _Float16 h2   __attribute__((ext_vector_type(2)));
typedef unsigned u4v  __attribute__((ext_vector_type(4)));

__device__ inline ushortT f2bf(float x){
  union{float f; unsigned u;} v; v.f = x;
  unsigned r = v.u + 0x7fffu + ((v.u >> 16) & 1u);   // RNE
  return (ushortT)(r >> 16);
}
__device__ inline float bf2f(ushortT h){
  union{unsigned u; float f;} v; v.u = ((unsigned)h) << 16;
  return v.f;
}
__device__ inline ushortT f2h(float x){
  union{_Float16 h; ushortT u;} v; v.h = (_Float16)x;
  return v.u;
}
__device__ inline float h2f(ushortT u){
  union{ushortT u; _Float16 h;} v; v.u = u;
  return (float)v.h;
}
__device__ inline h2 pkmax(h2 a, h2 b){ return __builtin_elementwise_max(a, b); }
__device__ inline h2 u2h(unsigned u){ union{unsigned u; h2 h;} v{u}; return v.h; }

struct WSrc { const float* p[22]; };

// ============================ chunk sort (binning, no global scatter) ============================

template<int RANGE, bool LAB>
__device__ void sort_chunk(const int* __restrict__ edges, int E, int c,
                           unsigned* __restrict__ slab, int* __restrict__ offC,
                           int* __restrict__ btot,
                           unsigned* slds, int* hist, int* pfx){
  int tid = threadIdx.x;
  int base = c*2048;
  int cnt = E - base; if (cnt > 2048) cnt = 2048;
  hist[tid] = 0;
  __syncthreads();
  int bk[8]; unsigned pk[8];
  #pragma unroll
  for (int r=0;r<8;++r){
    int e = base + r*256 + tid;
    bk[r] = -1; pk[r] = 0;
    if (e < E){
      int s, d;
      if (LAB){ s = e; d = edges[e]; }
      else    { int2 ed = ((const int2*)edges)[e]; s = ed.x; d = ed.y; }
      int b = d / RANGE;
      bk[r] = b;
      pk[r] = ((unsigned)s << 11) | (unsigned)(d - b*RANGE);
      atomicAdd(&hist[b], 1);
    }
  }
  __syncthreads();
  int own = hist[tid];
  pfx[tid] = own;
  __syncthreads();
  for (int st=1; st<256; st<<=1){
    int x = (tid >= st) ? pfx[tid-st] : 0;
    __syncthreads();
    pfx[tid] += x;
    __syncthreads();
  }
  int excl = pfx[tid] - own;
  offC[(size_t)c*257 + tid] = excl;
  if (tid == 0) offC[(size_t)c*257 + 256] = cnt;
  if (own) atomicAdd(&btot[(c & (NCOPY-1))*NB + tid], own);
  hist[tid] = excl;          // running cursor
  __syncthreads();
  #pragma unroll
  for (int r=0;r<8;++r){
    if (bk[r] >= 0){
      int pos = atomicAdd(&hist[bk[r]], 1);
      slds[pos] = pk[r];
    }
  }
  __syncthreads();
  unsigned* sg = slab + (size_t)c*2048;
  for (int i=tid; i<cnt; i+=256) sg[i] = slds[i];
}

// ============================ CSR build (cooperative slab gather) ============================

template<int RANGE, int NCHUNK, int K>
__device__ void csr_build_seg(const unsigned* __restrict__ slab, const int* __restrict__ offC,
                              const int* __restrict__ btot,
                              int n, int* __restrict__ offs, int* __restrict__ csr,
                              int b, unsigned* stage, int* hist, int* part,
                              ushortT* mstA, ushortT* mlenA, ushortT* sbA){
  constexpr int CPT = (NCHUNK + 255) / 256;
  int tid = threadIdx.x;
  int dlo = b*RANGE;
  int range = n - dlo; if (range > RANGE) range = RANGE; if (range < 0) range = 0;
  // ---- sum striped partial totals, then exclusive prefix over 256 buckets ----
  int ownT = 0;
  #pragma unroll
  for (int k=0;k<NCOPY;++k) ownT += btot[k*NB + tid];
  part[tid] = ownT;
  __syncthreads();
  for (int st=1; st<256; st<<=1){
    int x = (tid >= st) ? part[tid-st] : 0;
    __syncthreads();
    part[tid] += x;
    __syncthreads();
  }
  int totB = part[b];
  int total = part[NB-1];
  if (b == NB-1 && tid == 0) offs[n] = total;
  __syncthreads();                 // part[] is reused below
  // ---- per-chunk meta for this bucket ----
  int mst[CPT], mlen[CPT];
  int csum = 0;
  #pragma unroll
  for (int k=0;k<CPT;++k){
    int c = tid + k*256;
    int l = 0, s0 = 0;
    if (c < NCHUNK){
      s0 = offC[(size_t)c*257 + b];
      l  = offC[(size_t)c*257 + b + 1] - s0;
    }
    mst[k] = s0; mlen[k] = l; csum += l;
  }
  part[tid] = csum;
  __syncthreads();
  int own2 = csum;
  for (int st=1; st<256; st<<=1){
    int x = (tid >= st) ? part[tid-st] : 0;
    __syncthreads();
    part[tid] += x;
    __syncthreads();
  }
  int cnt = part[NB-1];
  int gb = totB - cnt;
  int sb = part[tid] - own2;
  #pragma unroll
  for (int k=0;k<CPT;++k){
    int c = tid + k*256;
    if (c < NCHUNK){
      mstA[c] = (ushortT)mst[k];
      mlenA[c] = (ushortT)mlen[k];
      sbA[c] = (ushortT)sb;
      sb += mlen[k];
    }
  }
  __syncthreads();
  // ---- cooperative gather: 2 lanes per chunk, 16B loads ----
  int wv = tid >> 6, l = tid & 63;
  for (int cb = wv*32; cb < NCHUNK; cb += 128){
    int c = cb + (l >> 1);
    if (c < NCHUNK){
      int len = mlenA[c];
      int half = l & 1;
      if (half*4 < len){
        const unsigned* sg = slab + (size_t)c*2048 + mstA[c];
        int sbc = sbA[c];
        for (int j = half*4; j < len; j += 8){
          unsigned v[4];
          __builtin_memcpy(v, sg + j, 16);
          #pragma unroll
          for (int q=0;q<4;++q) if (j+q < len) stage[sbc+j+q] = v[q];
        }
      }
    }
  }
  __syncthreads();
  // ---- histogram by local dst ----
  for (int t=tid; t<RANGE; t+=256) hist[t] = 0;
  __syncthreads();
  for (int j=tid; j<cnt; j+=256) atomicAdd(&hist[stage[j] & 2047u], 1);
  __syncthreads();
  int s = 0; int loc[K];
  #pragma unroll
  for (int kk=0; kk<K; ++kk){
    int idx = tid*K + kk;
    int v = (idx < RANGE) ? hist[idx] : 0;
    loc[kk] = s; s += v;
  }
  part[tid] = s; __syncthreads();
  int own3 = s;
  for (int st=1; st<256; st<<=1){
    int x = (tid >= st) ? part[tid-st] : 0;
    __syncthreads();
    part[tid] += x;
    __syncthreads();
  }
  int ebase = part[tid] - own3;
  __syncthreads();
  #pragma unroll
  for (int kk=0; kk<K; ++kk){
    int idx = tid*K + kk;
    if (idx < RANGE){
      int ex = ebase + loc[kk];
      if (idx < range) offs[dlo+idx] = gb + ex;
      hist[idx] = ex;
    }
  }
  __syncthreads();
  for (int j=tid; j<cnt; j+=256){
    unsigned p = stage[j];
    int pos = atomicAdd(&hist[p & 2047u], 1);
    csr[gb + pos] = (int)(p >> 11);
  }
}

__global__ __launch_bounds__(256) void k_build_all(
    const unsigned* s0, const int* oc0, const int* bt0, int* offs0, int* csr0,
    const unsigned* s1, const int* oc1, const int* bt1, int* offs1, int* csr1,
    const unsigned* sL, const int* ocL, const int* btL, int* offsL, int* csrL){
  __shared__ unsigned stage[CAP0];
  __shared__ int hist[RANGE0];
  __shared__ int part[256];
  __shared__ ushortT mstA[NCH0];
  __shared__ ushortT mlenA[NCH0];
  __shared__ ushortT sbA[NCH0];
  int b = blockIdx.x;
  if (b < 256)      csr_build_seg<RANGE0,NCH0,2>(s0, oc0, bt0, N_PTS, offs0, csr0, b, stage, hist, part, mstA, mlenA, sbA);
  else if (b < 512) csr_build_seg<RANGE1,NCH1,1>(s1, oc1, bt1, M_CL, offs1, csr1, b-256, stage, hist, part, mstA, mlenA, sbA);
  else              csr_build_seg<RANGE1,NCHL,1>(sL, ocL, btL, M_CL, offsL, csrL, b-512, stage, hist, part, mstA, mlenA, sbA);
}

// ============================ FUSED: wprep (17) + chunk sort (1027) + f1g ============================
// blocks [0,17): weight prep; [17,1044): sort chunks; [1044, 1044+nf1blk): f1g.
// f1g loads its 8 weight fragments directly from float mWe (same f2bf bits) ->
// no dependency on the wprep blocks.

__global__ __launch_bounds__(256) void k_bin_f1g(
    WSrc s, ushortT* __restrict__ wt, ushortT* __restrict__ wtc, float* __restrict__ wpp,
    const int* __restrict__ l0e, const int* __restrict__ l1e, const int* __restrict__ labels,
    int* bt0, int* bt1, int* btL,
    unsigned* sl0, unsigned* sl1, unsigned* slL,
    int* oc0, int* oc1, int* ocL,
    const float* __restrict__ features, const float* __restrict__ points,
    const float* __restrict__ centers,
    const float* __restrict__ W, const float* __restrict__ bfe,
    const float* __restrict__ bias2, const float* __restrict__ We,
    float* __restrict__ rel, ushortT* __restrict__ f1b,
    ushortT* __restrict__ gout, int n, int ntiles, int nf1blk)
{
  __shared__ char smem[10240];   // bin: slds 8192 + hist 1024 + pfx 1024; f1g: 9216
  int b = blockIdx.x;
  if (b < 17){
    // ---- weight prep (K-permuted): slots 0-14 wt, 15 wtc, 16 wpp ----
    int slot = b;
    if (slot < 15){
      const float* src = s.p[slot];
      ushortT* dst = wt + slot*4096;
      for (int e=threadIdx.x; e<4096; e+=256){
        int nn = e>>6, p = e&63;
        int kk = (p&3)*16 + (p>>2);
        dst[e] = f2bf(src[kk*64+nn]);
      }
    } else if (slot == 15){
      const float* src = s.p[15];
      for (int e=threadIdx.x; e<1024; e+=256){
        int nn = e>>6, p = e&63;
        int kk = (p&3)*16 + (p>>2);
        wtc[e] = (nn<8) ? f2bf(src[kk*8+nn]) : (ushortT)0;
      }
    } else {
      for (int e=threadIdx.x; e<6*192; e+=256){
        int i = e/192, rem = e - i*192, r = rem>>6, p = rem&63;
        wpp[e] = s.p[16+i][r*64 + ((p&3)*16 + (p>>2))];
      }
    }
    return;
  }
  b -= 17;
  if (b < 1027){
    unsigned* slds = (unsigned*)smem;
    int* hist = (int*)(smem + 8192);
    int* pfx  = (int*)(smem + 9216);
    if (b < 782)      sort_chunk<RANGE0,false>(l0e, E0_N, b,     sl0, oc0, bt0, slds, hist, pfx);
    else if (b < 978) sort_chunk<RANGE1,false>(l1e, E1_N, b-782, sl1, oc1, bt1, slds, hist, pfx);
    else              sort_chunk<RANGE1,true >(labels, N_PTS, b-978, slL, ocL, btL, slds, hist, pfx);
    return;
  }
  // ---- f1g: rel + f1 (bf16, permuted cols) + g0' (f16, permuted cols) ----
  ushortT* lds = (ushortT*)smem;
  int bb = b - 1027;
  int tid = threadIdx.x;
  int lane = tid & 63, wslot = tid >> 6;
  int quad = lane >> 4, l15 = lane & 15;
  int permL = (lane & 15)*4 + (lane >> 4);   // physical slot of logical col `lane`
  int r3 = lane/3, c3 = lane - r3*3;         // 48-lane pos mapping
  int gw = (bb*256 + tid) >> 6;
  int nw = (nf1blk*256) >> 6;
  float Wf0=W[0*64+lane], Wf1=W[1*64+lane], Wf2=W[2*64+lane], Wf3=W[3*64+lane];
  float wr0=W[4*64+lane], wr1=W[5*64+lane], wr2=W[6*64+lane];
  float bias=bfe[lane];
  // direct-from-float weight fragments (identical bits to wt path)
  const float* Wk = We + 192;   // [64 k][64 n]
  auto ldf = [&](int nn, int pbase)->short8{
    short8 r;
    #pragma unroll
    for (int e=0;e<8;++e){
      int p = pbase + e;
      int kk = (p&3)*16 + (p>>2);
      r[e] = (short)f2bf(Wk[kk*64 + nn]);
    }
    return r;
  };
  short8 s0_0 = ldf(l15, quad*8),      s0_1 = ldf(l15, 32+quad*8);
  short8 s1_0 = ldf(16+l15, quad*8),   s1_1 = ldf(16+l15, 32+quad*8);
  short8 s2_0 = ldf(32+l15, quad*8),   s2_1 = ldf(32+l15, 32+quad*8);
  short8 s3_0 = ldf(48+l15, quad*8),   s3_1 = ldf(48+l15, 32+quad*8);
  float eb0 = bias2[l15], eb1 = bias2[16+l15], eb2 = bias2[32+l15], eb3 = bias2[48+l15];
  float e0c0=We[0*64+l15], e0c1=We[0*64+16+l15], e0c2=We[0*64+32+l15], e0c3=We[0*64+48+l15];
  float e1c0=We[1*64+l15], e1c1=We[1*64+16+l15], e1c2=We[1*64+32+l15], e1c3=We[1*64+48+l15];
  float e2c0=We[2*64+l15], e2c1=We[2*64+16+l15], e2c2=We[2*64+32+l15], e2c3=We[2*64+48+l15];

  for (int t=gw; t<ntiles; t+=nw){
    int i0 = t*16;
    // ---- cooperative stage: labels(16), features(64), points(48), centers-gather(48) ----
    int lab16 = labels[min(i0 + (lane & 15), n-1)];
    float fv  = features[(size_t)min(i0 + (lane>>2), n-1)*4 + (lane & 3)];
    int lb = __shfl(lab16, (r3 < 16) ? r3 : 0, 64);
    float pv = 0.f, relv = 0.f;
    if (lane < 48){
      int rowp = i0 + r3;
      int rc = (rowp < n) ? rowp : (n-1);
      pv = points[(size_t)rc*3 + c3];
      float cv = centers[(size_t)lb*3 + c3];
      relv = pv - cv;
      if (rowp < n) rel[(size_t)rowp*3 + c3] = relv;
    }
    #pragma unroll
    for (int r=0;r<16;++r){
      float rx = __shfl(relv, 3*r+0, 64);
      float ry = __shfl(relv, 3*r+1, 64);
      float rz = __shfl(relv, 3*r+2, 64);
      float f0 = __shfl(fv, 4*r+0, 64);
      float f1 = __shfl(fv, 4*r+1, 64);
      float f2 = __shfl(fv, 4*r+2, 64);
      float f3 = __shfl(fv, 4*r+3, 64);
      float acc = bias + wr0*rx + wr1*ry + wr2*rz;
      acc += f0*Wf0 + f1*Wf1;
      acc += f2*Wf2 + f3*Wf3;
      acc = fmaxf(acc, 0.f);
      ushortT ab = f2bf(acc);
      int row = i0 + r;
      if (row < n) f1b[(size_t)row*64 + permL] = ab;
      lds[wslot*(16*LSTR) + r*LSTR + permL] = ab;
    }
    __builtin_amdgcn_wave_barrier();
    const ushortT* lp = lds + wslot*(16*LSTR) + l15*LSTR + quad*8;
    short8 sa0 = *(const short8*)(lp);
    short8 sa1 = *(const short8*)(lp + 32);
    __builtin_amdgcn_wave_barrier();
    v4f ec0 = {0.f,0.f,0.f,0.f}, ec1 = ec0, ec2 = ec0, ec3 = ec0;
    ec0 = __builtin_amdgcn_mfma_f32_16x16x32_bf16(sa0, s0_0, ec0, 0,0,0);
    ec1 = __builtin_amdgcn_mfma_f32_16x16x32_bf16(sa0, s1_0, ec1, 0,0,0);
    ec2 = __builtin_amdgcn_mfma_f32_16x16x32_bf16(sa0, s2_0, ec2, 0,0,0);
    ec3 = __builtin_amdgcn_mfma_f32_16x16x32_bf16(sa0, s3_0, ec3, 0,0,0);
    ec0 = __builtin_amdgcn_mfma_f32_16x16x32_bf16(sa1, s0_1, ec0, 0,0,0);
    ec1 = __builtin_amdgcn_mfma_f32_16x16x32_bf16(sa1, s1_1, ec1, 0,0,0);
    ec2 = __builtin_amdgcn_mfma_f32_16x16x32_bf16(sa1, s2_1, ec2, 0,0,0);
    ec3 = __builtin_amdgcn_mfma_f32_16x16x32_bf16(sa1, s3_1, ec3, 0,0,0);
    #pragma unroll
    for (int r=0;r<4;++r){
      int row = i0 + quad*4 + r;
      if (row < n){
        int rr4 = quad*4 + r;
        float vx = __shfl(pv, 3*rr4+0, 64);
        float vy = __shfl(pv, 3*rr4+1, 64);
        float vz = __shfl(pv, 3*rr4+2, 64);
        float g0 = ec0[r] + eb0 + vx*e0c0 + vy*e1c0 + vz*e2c0;
        float g1 = ec1[r] + eb1 + vx*e0c1 + vy*e1c1 + vz*e2c1;
        float g2 = ec2[r] + eb2 + vx*e0c2 + vy*e1c2 + vz*e2c2;
        float g3 = ec3[r] + eb3 + vx*e0c3 + vy*e1c3 + vz*e2c3;
        s4v o; o.x=(short)f2h(g0); o.y=(short)f2h(g1); o.z=(short)f2h(g2); o.w=(short)f2h(g3);
        *(s4v*)(gout + (size_t)row*64 + l15*4) = o;
      }
    }
  }
}

// ============================ MFMA GEMM with optional fused secondary GEMM ============================

template<bool RELU, int NRES, bool USEREL, bool GATHER, bool OUT16, bool F16O, int EMODE, bool ERELU>
__global__ __launch_bounds__(256) void k_gemm(
    const ushortT* __restrict__ A, const ushortT* __restrict__ Wt,
    const float* __restrict__ bias, const float* __restrict__ Wr,
    const float* __restrict__ rel, const int* __restrict__ gidx,
    const ushortT* __restrict__ r1, const ushortT* __restrict__ r2,
    ushortT* __restrict__ out16,
    const ushortT* __restrict__ Wt2, const float* __restrict__ bias2,
    const float* __restrict__ Wr2, const float* __restrict__ vec2,
    void* __restrict__ eout,
    int n, int ntiles)
{
  constexpr int LDSZ = (EMODE>0) ? 4*16*LSTR : 4;
  __shared__ ushortT lds[LDSZ];
  int tid = threadIdx.x;
  int lane = tid & 63, wslot = tid >> 6;
  int quad = lane >> 4, l15 = lane & 15;
  int r3 = lane/3, c3 = lane - r3*3;
  int gw = (blockIdx.x*256 + tid) >> 6;
  int nw = (gridDim.x*256) >> 6;

  short8 bfr0_0 = *(const short8*)(Wt + ( 0 + l15)*64 +  0 + quad*8);
  short8 bfr0_1 = *(const short8*)(Wt + ( 0 + l15)*64 + 32 + quad*8);
  short8 bfr1_0 = *(const short8*)(Wt + (16 + l15)*64 +  0 + quad*8);
  short8 bfr1_1 = *(const short8*)(Wt + (16 + l15)*64 + 32 + quad*8);
  short8 bfr2_0 = *(const short8*)(Wt + (32 + l15)*64 +  0 + quad*8);
  short8 bfr2_1 = *(const short8*)(Wt + (32 + l15)*64 + 32 + quad*8);
  short8 bfr3_0 = *(const short8*)(Wt + (48 + l15)*64 +  0 + quad*8);
  short8 bfr3_1 = *(const short8*)(Wt + (48 + l15)*64 + 32 + quad*8);
  float bs0 = bias[ 0 + l15], bs1 = bias[16 + l15];
  float bs2 = bias[32 + l15], bs3 = bias[48 + l15];
  float w0c0=0,w0c1=0,w0c2=0,w0c3=0, w1c0=0,w1c1=0,w1c2=0,w1c3=0, w2c0=0,w2c1=0,w2c2=0,w2c3=0;
  if (USEREL){
    w0c0=Wr[0*64+l15]; w0c1=Wr[0*64+16+l15]; w0c2=Wr[0*64+32+l15]; w0c3=Wr[0*64+48+l15];
    w1c0=Wr[1*64+l15]; w1c1=Wr[1*64+16+l15]; w1c2=Wr[1*64+32+l15]; w1c3=Wr[1*64+48+l15];
    w2c0=Wr[2*64+l15]; w2c1=Wr[2*64+16+l15]; w2c2=Wr[2*64+32+l15]; w2c3=Wr[2*64+48+l15];
  }

  short8 s0_0{}, s0_1{}, s1_0{}, s1_1{}, s2_0{}, s2_1{}, s3_0{}, s3_1{};
  float eb0=0, eb1=0, eb2=0, eb3=0;
  float e0c0=0,e0c1=0,e0c2=0,e0c3=0, e1c0=0,e1c1=0,e1c2=0,e1c3=0, e2c0=0,e2c1=0,e2c2=0,e2c3=0;
  float ebias_c = 0.f;
  if (EMODE == 1){
    s0_0 = *(const short8*)(Wt2 + ( 0 + l15)*64 +  0 + quad*8);
    s0_1 = *(const short8*)(Wt2 + ( 0 + l15)*64 + 32 + quad*8);
    s1_0 = *(const short8*)(Wt2 + (16 + l15)*64 +  0 + quad*8);
    s1_1 = *(const short8*)(Wt2 + (16 + l15)*64 + 32 + quad*8);
    s2_0 = *(const short8*)(Wt2 + (32 + l15)*64 +  0 + quad*8);
    s2_1 = *(const short8*)(Wt2 + (32 + l15)*64 + 32 + quad*8);
    s3_0 = *(const short8*)(Wt2 + (48 + l15)*64 +  0 + quad*8);
    s3_1 = *(const short8*)(Wt2 + (48 + l15)*64 + 32 + quad*8);
    eb0 = bias2[l15]; eb1 = bias2[16+l15]; eb2 = bias2[32+l15]; eb3 = bias2[48+l15];
    e0c0=Wr2[0*64+l15]; e0c1=Wr2[0*64+16+l15]; e0c2=Wr2[0*64+32+l15]; e0c3=Wr2[0*64+48+l15];
    e1c0=Wr2[1*64+l15]; e1c1=Wr2[1*64+16+l15]; e1c2=Wr2[1*64+32+l15]; e1c3=Wr2[1*64+48+l15];
    e2c0=Wr2[2*64+l15]; e2c1=Wr2[2*64+16+l15]; e2c2=Wr2[2*64+32+l15]; e2c3=Wr2[2*64+48+l15];
  } else if (EMODE == 2){
    s0_0 = *(const short8*)(Wt2 + l15*64 +  0 + quad*8);
    s0_1 = *(const short8*)(Wt2 + l15*64 + 32 + quad*8);
    ebias_c = (l15 < 8) ? bias2[l15] : 0.f;
  }

  for (int t=gw; t<ntiles; t+=nw){
    int i0 = t*16;
    int rowA = i0 + l15; if (rowA >= n) rowA = n-1;
    if (GATHER) rowA = gidx[rowA];
    const ushortT* ap = A + (size_t)rowA*64 + quad*8;
    short8 a0 = *(const short8*)(ap);
    short8 a1 = *(const short8*)(ap + 32);
    float relL = 0.f;
    if (USEREL && lane < 48){
      int rc = i0 + r3; if (rc >= n) rc = n-1;
      relL = rel[(size_t)rc*3 + c3];
    }
    v4f ac0 = {0.f,0.f,0.f,0.f}, ac1 = ac0, ac2 = ac0, ac3 = ac0;
    ac0 = __builtin_amdgcn_mfma_f32_16x16x32_bf16(a0, bfr0_0, ac0, 0,0,0);
    ac1 = __builtin_amdgcn_mfma_f32_16x16x32_bf16(a0, bfr1_0, ac1, 0,0,0);
    ac2 = __builtin_amdgcn_mfma_f32_16x16x32_bf16(a0, bfr2_0, ac2, 0,0,0);
    ac3 = __builtin_amdgcn_mfma_f32_16x16x32_bf16(a0, bfr3_0, ac3, 0,0,0);
    ac0 = __builtin_amdgcn_mfma_f32_16x16x32_bf16(a1, bfr0_1, ac0, 0,0,0);
    ac1 = __builtin_amdgcn_mfma_f32_16x16x32_bf16(a1, bfr1_1, ac1, 0,0,0);
    ac2 = __builtin_amdgcn_mfma_f32_16x16x32_bf16(a1, bfr2_1, ac2, 0,0,0);
    ac3 = __builtin_amdgcn_mfma_f32_16x16x32_bf16(a1, bfr3_1, ac3, 0,0,0);

    #pragma unroll
    for (int r=0;r<4;++r){
      int row = i0 + quad*4 + r;
      bool rowok = (row < n);
      float v0 = ac0[r] + bs0, v1 = ac1[r] + bs1, v2 = ac2[r] + bs2, v3 = ac3[r] + bs3;
      if (USEREL){
        int rr4 = quad*4 + r;
        float rx = __shfl(relL, 3*rr4+0, 64);
        float ry = __shfl(relL, 3*rr4+1, 64);
        float rz = __shfl(relL, 3*rr4+2, 64);
        v0 += rx*w0c0 + ry*w1c0 + rz*w2c0;
        v1 += rx*w0c1 + ry*w1c1 + rz*w2c1;
        v2 += rx*w0c2 + ry*w1c2 + rz*w2c2;
        v3 += rx*w0c3 + ry*w1c3 + rz*w2c3;
      }
      if (RELU){ v0=fmaxf(v0,0.f); v1=fmaxf(v1,0.f); v2=fmaxf(v2,0.f); v3=fmaxf(v3,0.f); }
      size_t pb = (size_t)row*64 + l15*4;
      if (rowok){
        if (NRES>=1){
          s4v rv = *(const s4v*)(r1 + pb);
          v0 += bf2f((ushortT)rv.x); v1 += bf2f((ushortT)rv.y);
          v2 += bf2f((ushortT)rv.z); v3 += bf2f((ushortT)rv.w);
        }
        if (NRES>=2){
          s4v rv = *(const s4v*)(r2 + pb);
          v0 += bf2f((ushortT)rv.x); v1 += bf2f((ushortT)rv.y);
          v2 += bf2f((ushortT)rv.z); v3 += bf2f((ushortT)rv.w);
        }
        if (OUT16){
          s4v o;
          if (F16O){ o.x=(short)f2h(v0); o.y=(short)f2h(v1); o.z=(short)f2h(v2); o.w=(short)f2h(v3); }
          else     { o.x=(short)f2bf(v0); o.y=(short)f2bf(v1); o.z=(short)f2bf(v2); o.w=(short)f2bf(v3); }
          *(s4v*)(out16 + pb) = o;
        }
      }
      if (EMODE > 0){
        int lb = wslot*(16*LSTR) + (quad*4+r)*LSTR + l15*4;
        s4v o; o.x=(short)f2bf(v0); o.y=(short)f2bf(v1); o.z=(short)f2bf(v2); o.w=(short)f2bf(v3);
        *(s4v*)(lds + lb) = o;
      }
    }

    if (EMODE > 0){
      __builtin_amdgcn_wave_barrier();
      const ushortT* lp = lds + wslot*(16*LSTR) + l15*LSTR + quad*8;
      short8 sa0 = *(const short8*)(lp);
      short8 sa1 = *(const short8*)(lp + 32);
      __builtin_amdgcn_wave_barrier();
      if (EMODE == 1){
        float posv = 0.f;
        if (lane < 48){
          int rc = i0 + r3; if (rc >= n) rc = n-1;
          posv = vec2[(size_t)rc*3 + c3];
        }
        v4f ec0 = {0.f,0.f,0.f,0.f}, ec1 = ec0, ec2 = ec0, ec3 = ec0;
        ec0 = __builtin_amdgcn_mfma_f32_16x16x32_bf16(sa0, s0_0, ec0, 0,0,0);
        ec1 = __builtin_amdgcn_mfma_f32_16x16x32_bf16(sa0, s1_0, ec1, 0,0,0);
        ec2 = __builtin_amdgcn_mfma_f32_16x16x32_bf16(sa0, s2_0, ec2, 0,0,0);
        ec3 = __builtin_amdgcn_mfma_f32_16x16x32_bf16(sa0, s3_0, ec3, 0,0,0);
        ec0 = __builtin_amdgcn_mfma_f32_16x16x32_bf16(sa1, s0_1, ec0, 0,0,0);
        ec1 = __builtin_amdgcn_mfma_f32_16x16x32_bf16(sa1, s1_1, ec1, 0,0,0);
        ec2 = __builtin_amdgcn_mfma_f32_16x16x32_bf16(sa1, s2_1, ec2, 0,0,0);
        ec3 = __builtin_amdgcn_mfma_f32_16x16x32_bf16(sa1, s3_1, ec3, 0,0,0);
        ushortT* eo = (ushortT*)eout;
        #pragma unroll
        for (int r=0;r<4;++r){
          int row = i0 + quad*4 + r;
          if (row < n){
            int rr4 = quad*4 + r;
            float vx = __shfl(posv, 3*rr4+0, 64);
            float vy = __shfl(posv, 3*rr4+1, 64);
            float vz = __shfl(posv, 3*rr4+2, 64);
            float g0 = ec0[r] + eb0 + vx*e0c0 + vy*e1c0 + vz*e2c0;
            float g1 = ec1[r] + eb1 + vx*e0c1 + vy*e1c1 + vz*e2c1;
            float g2 = ec2[r] + eb2 + vx*e0c2 + vy*e1c2 + vz*e2c2;
            float g3 = ec3[r] + eb3 + vx*e0c3 + vy*e1c3 + vz*e2c3;
            if (ERELU){ g0=fmaxf(g0,0.f); g1=fmaxf(g1,0.f); g2=fmaxf(g2,0.f); g3=fmaxf(g3,0.f); }
            s4v o; o.x=(short)f2h(g0); o.y=(short)f2h(g1); o.z=(short)f2h(g2); o.w=(short)f2h(g3);
            *(s4v*)(eo + (size_t)row*64 + l15*4) = o;
          }
        }
      } else {
        v4f ec = {0.f,0.f,0.f,0.f};
        ec = __builtin_amdgcn_mfma_f32_16x16x32_bf16(sa0, s0_0, ec, 0,0,0);
        ec = __builtin_amdgcn_mfma_f32_16x16x32_bf16(sa1, s0_1, ec, 0,0,0);
        if (l15 < 8){
          float* eo = (float*)eout;
          #pragma unroll
          for (int r=0;r<4;++r){
            int row = i0 + quad*4 + r;
            if (row < n) eo[(size_t)row*8 + l15] = ec[r] + ebias_c;
          }
        }
      }
    }
  }
}

// ============================ edge aggregation: 8 dsts/wave, 8 lanes per dst (R0 shape) ============================

__global__ __launch_bounds__(256) void k_edge_agg(const int* __restrict__ offs, const int* __restrict__ csr,
                                                  const float* __restrict__ pos, const ushortT* __restrict__ g,
                                                  const float* __restrict__ Wp, ushortT* __restrict__ agg, int n){
  int lane = threadIdx.x & 63;
  int grp = lane >> 3, d8 = lane & 7;
  int gbase = lane & 56;
  int gw = (blockIdx.x*256 + threadIdx.x) >> 6;
  int nw = (gridDim.x*256) >> 6;
  const u4v* g4 = (const u4v*)g;
  float2 w0[4], w1[4], w2[4];
  #pragma unroll
  for (int q=0;q<4;++q){
    w0[q] = *(const float2*)(Wp + 0*64 + d8*8 + 2*q);
    w1[q] = *(const float2*)(Wp + 1*64 + d8*8 + 2*q);
    w2[q] = *(const float2*)(Wp + 2*64 + d8*8 + 2*q);
  }
  const h2 NEGBIG = {(_Float16)-60000.f, (_Float16)-60000.f};
  int n8 = (n+7) >> 3;
  for (int ii=gw; ii<n8; ii+=nw){
    int i0 = ii*8;
    int ig = i0 + grp; bool ok = ig < n; if (!ok) ig = n-1;
    int b = offs[ig], e = offs[ig+1];
    int cnt = e - b, c1 = cnt - 1;
    int mx = cnt;
    mx = max(mx, __shfl_xor(mx, 8, 64));
    mx = max(mx, __shfl_xor(mx, 16, 64));
    mx = max(mx, __shfl_xor(mx, 32, 64));
    h2 m0=NEGBIG, m1=NEGBIG, m2=NEGBIG, m3=NEGBIG;
    for (int J=0; J<mx; J+=8){
      if (J < cnt){
        int sv = csr[b + min(J + d8, c1)];
        #pragma unroll
        for (int jj=0; jj<8; ++jj){
          int s = __shfl(sv, gbase + jj, 64);
          u4v u = g4[(size_t)s*8 + d8];
          m0 = pkmax(m0, u2h(u.x));
          m1 = pkmax(m1, u2h(u.y));
          m2 = pkmax(m2, u2h(u.z));
          m3 = pkmax(m3, u2h(u.w));
        }
      }
    }
    float px = pos[ig*3+0], py = pos[ig*3+1], pz = pos[ig*3+2];
    u4v outv;
    {
      float sA = w0[0].x*px + w1[0].x*py + w2[0].x*pz;
      float sB = w0[0].y*px + w1[0].y*py + w2[0].y*pz;
      outv.x = (unsigned)f2bf(fmaxf((float)m0.x - sA, 0.f)) |
               ((unsigned)f2bf(fmaxf((float)m0.y - sB, 0.f)) << 16);
    }
    {
      float sA = w0[1].x*px + w1[1].x*py + w2[1].x*pz;
      float sB = w0[1].y*px + w1[1].y*py + w2[1].y*pz;
      outv.y = (unsigned)f2bf(fmaxf((float)m1.x - sA, 0.f)) |
               ((unsigned)f2bf(fmaxf((float)m1.y - sB, 0.f)) << 16);
    }
    {
      float sA = w0[2].x*px + w1[2].x*py + w2[2].x*pz;
      float sB = w0[2].y*px + w1[2].y*py + w2[2].y*pz;
      outv.z = (unsigned)f2bf(fmaxf((float)m2.x - sA, 0.f)) |
               ((unsigned)f2bf(fmaxf((float)m2.y - sB, 0.f)) << 16);
    }
    {
      float sA = w0[3].x*px + w1[3].x*py + w2[3].x*pz;
      float sB = w0[3].y*px + w1[3].y*py + w2[3].y*pz;
      outv.w = (unsigned)f2bf(fmaxf((float)m3.x - sA, 0.f)) |
               ((unsigned)f2bf(fmaxf((float)m3.y - sB, 0.f)) << 16);
    }
    if (ok) ((u4v*)agg)[(size_t)ig*8 + d8] = outv;
  }
}

// ============================ segment sum via label CSR (f16 in, bf16 out) ============================

__global__ __launch_bounds__(256) void k_seg_gather(const int* __restrict__ offs, const int* __restrict__ csr,
                                                    const ushortT* __restrict__ h, ushortT* __restrict__ c, int m){
  int lane = threadIdx.x & 63;
  int wv = (blockIdx.x*256 + threadIdx.x) >> 6;
  if (wv >= m) return;
  int b = offs[wv], e = offs[wv+1];
  float acc = 0.f;
  for (int k=b; k<e; ++k){
    int i = csr[k];
    acc += h2f(h[(size_t)i*64+lane]);
  }
  c[(size_t)wv*64+lane] = f2bf(acc);
}

// ============================ host launcher ============================

extern "C" void kernel_launch(void* const* d_in, const int* in_sizes, int n_in,
                              void* d_out, int out_size, void* d_ws, size_t ws_size,
                              hipStream_t stream){
  const float* features = (const float*)d_in[0];
  const float* points   = (const float*)d_in[1];
  const float* centers  = (const float*)d_in[2];
  const int*   l0e      = (const int*)d_in[3];
  const int*   l1e      = (const int*)d_in[4];
  const int*   labels   = (const int*)d_in[5];
  const float* W_fe = (const float*)d_in[6];
  const float* b_fe = (const float*)d_in[7];
  const float* mWe  = (const float*)d_in[8];
  const float* mbe  = (const float*)d_in[9];
  const float* mWu  = (const float*)d_in[10];
  const float* mbu  = (const float*)d_in[11];
  const float* W_m1 = (const float*)d_in[12];
  const float* b_m1 = (const float*)d_in[13];
  const float* W_m2 = (const float*)d_in[14];
  const float* b_m2 = (const float*)d_in[15];
  const float* gWe  = (const float*)d_in[16];
  const float* gbe  = (const float*)d_in[17];
  const float* gWu  = (const float*)d_in[18];
  const float* gbu  = (const float*)d_in[19];
  const float* W_l  = (const float*)d_in[20];
  const float* b_l  = (const float*)d_in[21];
  const float* W_c  = (const float*)d_in[22];
  const float* b_c  = (const float*)d_in[23];
  float* out = (float*)d_out;

  char* w = (char*)d_ws;
  size_t off = 0;
  auto alloc = [&](size_t bytes)->void*{
    void* p = (void*)(w + off);
    off = (off + bytes + 255) & ~(size_t)255;
    return p;
  };
  float* rel  = (float*)alloc((size_t)N_PTS*3*4);
  ushortT* UF1 = (ushortT*)alloc((size_t)N_PTS*64*2);
  ushortT* UF2 = (ushortT*)alloc((size_t)N_PTS*64*2);
  ushortT* UF21= (ushortT*)alloc((size_t)N_PTS*64*2);
  ushortT* UF5 = (ushortT*)alloc((size_t)N_PTS*64*2);
  ushortT* UF6 = (ushortT*)alloc((size_t)N_PTS*64*2);
  ushortT* gbuf= (ushortT*)alloc((size_t)N_PTS*64*2);
  ushortT* abuf= (ushortT*)alloc((size_t)N_PTS*64*2);
  ushortT* cb_b= (ushortT*)alloc((size_t)M_CL*64*2);
  ushortT* UF3 = (ushortT*)alloc((size_t)M_CL*64*2);
  ushortT* UF4 = (ushortT*)alloc((size_t)M_CL*64*2);
  ushortT* cg_b= (ushortT*)alloc((size_t)M_CL*64*2);
  ushortT* cagg_b = (ushortT*)alloc((size_t)M_CL*64*2);
  ushortT* f41_b  = (ushortT*)alloc((size_t)M_CL*64*2);
  ushortT* wt  = (ushortT*)alloc((size_t)15*4096*2);
  ushortT* wtc = (ushortT*)alloc((size_t)1024*2);
  float* wpp = (float*)alloc((size_t)6*192*4);
  int* offs0 = (int*)alloc((size_t)(N_PTS+1)*4);
  int* csr0  = (int*)alloc((size_t)E0_N*4);
  int* offs1 = (int*)alloc((size_t)(M_CL+1)*4);
  int* csr1  = (int*)alloc((size_t)E1_N*4);
  int* offsL = (int*)alloc((size_t)(M_CL+1)*4);
  int* csrL  = (int*)alloc((size_t)N_PTS*4);
  unsigned* slab0 = (unsigned*)alloc((size_t)NCH0*2048*4);
  unsigned* slab1 = (unsigned*)alloc((size_t)NCH1*2048*4);
  unsigned* slabL = (unsigned*)alloc((size_t)NCHL*2048*4);
  int* offC0 = (int*)alloc((size_t)NCH0*257*4);
  int* offC1 = (int*)alloc((size_t)NCH1*257*4);
  int* offCL = (int*)alloc((size_t)NCHL*257*4);
  int* btotA = (int*)alloc((size_t)3*NCOPY*NB*4);
  int* btot0 = btotA;
  int* btot1 = btotA + NCOPY*NB;
  int* btotL = btotA + 2*NCOPY*NB;
  (void)ws_size; (void)in_sizes; (void)n_in; (void)out_size;

  const int NT_N = (N_PTS+15)/16;
  const int NT_M = (M_CL +15)/16;
  const int GBG_N = 1563;
  const int GBG_M = 196;
  const int GB_N  = 3125;
  const int GB_BIN = 17 + 1027;   // wprep + sort chunks

  WSrc ws{};
  ws.p[0]=mWu+0*4096; ws.p[1]=mWu+1*4096; ws.p[2]=mWu+2*4096; ws.p[3]=mWu+3*4096;
  ws.p[4]=W_m2; ws.p[5]=gWu+0*4096; ws.p[6]=gWu+1*4096;
  ws.p[7]=mWe+0*4288+192; ws.p[8]=mWe+1*4288+192; ws.p[9]=mWe+2*4288+192; ws.p[10]=mWe+3*4288+192;
  ws.p[11]=W_m1; ws.p[12]=W_l; ws.p[13]=gWe+0*4288+192; ws.p[14]=gWe+1*4288+192;
  ws.p[15]=W_c;
  ws.p[16]=mWe+0*4288; ws.p[17]=mWe+1*4288; ws.p[18]=mWe+2*4288; ws.p[19]=mWe+3*4288;
  ws.p[20]=gWe+0*4288; ws.p[21]=gWe+1*4288;

  hipMemsetAsync(btotA, 0, (size_t)3*NCOPY*NB*4, stream);
  k_bin_f1g<<<GB_BIN + GBG_N, 256, 0, stream>>>(ws, wt, wtc, wpp,
      l0e, l1e, labels, btot0, btot1, btotL,
      slab0, slab1, slabL, offC0, offC1, offCL,
      features, points, centers, W_fe, b_fe, mbe, mWe,
      rel, UF1, gbuf, N_PTS, NT_N, GBG_N);
  k_build_all<<<768, 256, 0, stream>>>(slab0, offC0, btot0, offs0, csr0,
                                       slab1, offC1, btot1, offs1, csr1,
                                       slabL, offCL, btotL, offsL, csrL);

  // ---- layer0: agg -> FUSED [f2 -> UF2] + [g1' -> gbuf] ----
  k_edge_agg<<<GB_N,256,0,stream>>>(offs0, csr0, points, gbuf, wpp+0*192, abuf, N_PTS);
  k_gemm<true,1,false,false,true,false,1,false><<<GBG_N,256,0,stream>>>(abuf, wt+0*4096, mbu+0,
      nullptr, nullptr, nullptr, UF1, nullptr, UF2,
      wt+8*4096, mbe+64, mWe+1*4288, points, gbuf, N_PTS, NT_N);
  // ---- layer1: agg -> FUSED [f2_1 -> UF21] + [h -> gbuf] ----
  k_edge_agg<<<GB_N,256,0,stream>>>(offs0, csr0, points, gbuf, wpp+1*192, abuf, N_PTS);
  k_gemm<true,1,false,false,true,false,1,true><<<GBG_N,256,0,stream>>>(abuf, wt+1*4096, mbu+64,
      nullptr, nullptr, nullptr, UF2, nullptr, UF21,
      wt+11*4096, b_m1, W_m1+4096, rel, gbuf, N_PTS, NT_N);
  // ---- c = segsum(h); FUSED [f3 -> UF3] + [cg0' -> cg_b] ----
  k_seg_gather<<<(M_CL*64+255)/256, 256, 0, stream>>>(offsL, csrL, gbuf, cb_b, M_CL);
  k_gemm<true,0,false,false,true,false,1,false><<<GBG_M,256,0,stream>>>(cb_b, wt+4*4096, b_m2,
      nullptr, nullptr, nullptr, nullptr, nullptr, UF3,
      wt+13*4096, gbe+0, gWe+0*4288, centers, cg_b, M_CL, NT_M);
  // ---- cluster layer0: agg -> FUSED [f4 -> UF4] + [cg1' -> cg_b] ----
  k_edge_agg<<<GBG_M,256,0,stream>>>(offs1, csr1, centers, cg_b, wpp+4*192, cagg_b, M_CL);
  k_gemm<true,1,false,false,true,false,1,false><<<GBG_M,256,0,stream>>>(cagg_b, wt+5*4096, gbu+0,
      nullptr, nullptr, nullptr, UF3, nullptr, UF4,
      wt+14*4096, gbe+64, gWe+1*4288, centers, cg_b, M_CL, NT_M);
  // ---- cluster layer1: agg -> f4_1 -> f41_b ----
  k_edge_agg<<<GBG_M,256,0,stream>>>(offs1, csr1, centers, cg_b, wpp+5*192, cagg_b, M_CL);
  k_gemm<true,1,false,false,true,false,0,false><<<GBG_M,256,0,stream>>>(cagg_b, wt+6*4096, gbu+64,
      nullptr, nullptr, nullptr, UF4, nullptr, f41_b,
      nullptr, nullptr, nullptr, nullptr, nullptr, M_CL, NT_M);
  // ---- FUSED [f5 -> UF5] + [g2' -> gbuf] ----
  k_gemm<true,0,true,true,true,false,1,false><<<GBG_N,256,0,stream>>>(f41_b, wt+12*4096, b_l,
      W_l+4096, rel, labels, nullptr, nullptr, UF5,
      wt+9*4096, mbe+128, mWe+2*4288, points, gbuf, N_PTS, NT_N);
  // ---- layer2: agg -> FUSED [f6 = relu+f5+f2_1 -> UF6] + [g3' -> gbuf] ----
  k_edge_agg<<<GB_N,256,0,stream>>>(offs0, csr0, points, gbuf, wpp+2*192, abuf, N_PTS);
  k_gemm<true,2,false,false,true,false,1,false><<<GBG_N,256,0,stream>>>(abuf, wt+2*4096, mbu+128,
      nullptr, nullptr, nullptr, UF5, UF21, UF6,
      wt+10*4096, mbe+192, mWe+3*4288, points, gbuf, N_PTS, NT_N);
  // ---- layer3: agg -> FUSED [final = relu+f6+f2] + [out = final@W_c + b_c] ----
  k_edge_agg<<<GB_N,256,0,stream>>>(offs0, csr0, points, gbuf, wpp+3*192, abuf, N_PTS);
  k_gemm<true,2,false,false,false,false,2,false><<<GBG_N,256,0,stream>>>(abuf, wt+3*4096, mbu+192,
      nullptr, nullptr, nullptr, UF6, UF2, nullptr,
      wtc, b_c, nullptr, nullptr, out, N_PTS, NT_N);
}